// Round 1
// 834.157 us; speedup vs baseline: 1.0213x; 1.0213x over previous
//
#include <hip/hip_runtime.h>
#include <hip/hip_bf16.h>
#include <math.h>

#define DEVI __device__ __forceinline__

typedef unsigned short u16;
typedef __attribute__((ext_vector_type(8))) __bf16 bf16x8;
typedef __attribute__((ext_vector_type(4))) float f32x4;
typedef __attribute__((ext_vector_type(8))) unsigned short u16x8;
typedef __attribute__((ext_vector_type(4))) unsigned short u16x4;

typedef __attribute__((address_space(1))) void gvoid;
typedef __attribute__((address_space(3))) void lvoid;

DEVI u16 f2bf(float f) {
  unsigned u = __builtin_bit_cast(unsigned, f);
  u += 0x7fffu + ((u >> 16) & 1u);   // RNE
  return (u16)(u >> 16);
}

DEVI f32x4 mfma_bf16(bf16x8 a, bf16x8 b, f32x4 c) {
  return __builtin_amdgcn_mfma_f32_16x16x32_bf16(a, b, c, 0, 0, 0);
}

DEVI void g2l16(const void* g, const void* l) {
  __builtin_amdgcn_global_load_lds((gvoid*)(size_t)g,
                                   (lvoid*)(unsigned)(size_t)l, 16, 0, 0);
}

// ---------------------------------------------------------------- fused small kernels
__global__ void sumsq3_k(const float* __restrict__ v0, const float* __restrict__ v1,
                         const float* __restrict__ v2, float* __restrict__ out)
{
  const int seg = blockIdx.x >> 7, wb = blockIdx.x & 127;
  const float* v = seg == 0 ? v0 : (seg == 1 ? v1 : v2);
  const int n4 = (seg == 1) ? 262144 : 524288;
  float s = 0.f;
  for (int i = wb * 256 + threadIdx.x; i < n4; i += 128 * 256) {
    f32x4 x = *(const f32x4*)(v + (size_t)i * 4);
    s += x.x * x.x + x.y * x.y + x.z * x.z + x.w * x.w;
  }
#pragma unroll
  for (int off = 32; off > 0; off >>= 1) s += __shfl_down(s, off);
  __shared__ float part[4];
  if ((threadIdx.x & 63) == 0) part[threadIdx.x >> 6] = s;
  __syncthreads();
  if (threadIdx.x == 0) atomicAdd(out + seg, part[0] + part[1] + part[2] + part[3]);
}

__global__ void wconv3_k(const float* __restrict__ v0, const float* __restrict__ v1,
                         const float* __restrict__ v2,
                         const float* __restrict__ g0, const float* __restrict__ g1,
                         const float* __restrict__ g2,
                         const float* __restrict__ ss,
                         u16* __restrict__ w0, u16* __restrict__ w1, u16* __restrict__ w2)
{
  const int i = blockIdx.x * 256 + threadIdx.x;  // f32x4 index over 1310720
  int seg, base;
  const float* v; u16* w;
  if (i < 524288)      { seg = 0; base = 0;      v = v0; w = w0; }
  else if (i < 786432) { seg = 1; base = 524288; v = v1; w = w1; }
  else                 { seg = 2; base = 786432; v = v2; w = w2; }
  const float* g = seg == 0 ? g0 : (seg == 1 ? g1 : g2);
  const float sc = g[0] / sqrtf(ss[seg]);
  const int j = i - base;
  f32x4 x = *(const f32x4*)(v + (size_t)j * 4);
  u16x4 o;
  o[0] = f2bf(x.x * sc); o[1] = f2bf(x.y * sc);
  o[2] = f2bf(x.z * sc); o[3] = f2bf(x.w * sc);
  *(u16x4*)(w + (size_t)j * 4) = o;
}

__global__ void cvt_k(const float* __restrict__ x, u16* __restrict__ y)
{
  const size_t i = (size_t)(blockIdx.x * blockDim.x + threadIdx.x) * 4;
  f32x4 v = *(const f32x4*)(x + i);
  u16x4 o;
  o[0] = f2bf(v.x); o[1] = f2bf(v.y); o[2] = f2bf(v.z); o[3] = f2bf(v.w);
  *(u16x4*)(y + i) = o;
}

__global__ void catleft_k(const float* __restrict__ tgt, u16* __restrict__ cat)
{
  const size_t e = (size_t)(blockIdx.x * blockDim.x + threadIdx.x) * 4;
  const int row = (int)(e >> 10), c = (int)(e & 1023);
  f32x4 x = *(const f32x4*)(tgt + e);
  u16x4 o;
  o[0] = f2bf(x.x); o[1] = f2bf(x.y); o[2] = f2bf(x.z); o[3] = f2bf(x.w);
  *(u16x4*)&cat[(size_t)row * 2048 + c] = o;
}

// ---------------------------------------------------------------- GEMM 256x256, 8-phase
// C = A @ B^T + bias. A [M][lda], B [N][K] bf16. BM=BN=256, BK=64, 512 thr (8 waves 2x4).
// LDS: per buffer, per matrix: [half(128 rows)][kplane(32 u16)] with XOR swizzle
//   slot c0 of row r holds global 16B-chunk (kplane*4 + (c0 ^ (r&3) ^ ((r>>2)&3))).
// 4 phases/K-tile: {ds_read frags | stage 1 unit of tile t+1 | barrier | lgkmcnt(0) |
//   setprio(1) 16 MFMA setprio(0) | barrier}. vmcnt(4) at phases 1,3 (counted, never 0
//   in main loop). Last tile peeled with vmcnt(0) at its phase 1.
// OUT_MODE: 0 = f32 (ldc), 1 = bf16 (ldc), 2 = split: cols<1024 -> st[.][1024],
//           cols>=1024 -> transposed into vt[b*8+h][128][1024].
template<int OUT_MODE, bool HAS_MASK>
__global__ __launch_bounds__(512, 2) void gemm_bt256(
    const u16* __restrict__ Ap, const u16* __restrict__ Bp,
    const float* __restrict__ bias, const float* __restrict__ rowmask,
    void* __restrict__ Cp, u16* __restrict__ C2p, int K, int lda, int ldc)
{
  __shared__ __align__(16) u16 As[32768];   // 2 buf x 2 half x 2 kplane x 128 x 32
  __shared__ __align__(16) u16 Bs[32768];
  const int tid = threadIdx.x;
  const int wave = tid >> 6, lane = tid & 63;
  const int l = lane & 15, q = lane >> 4;
  const int wm = wave >> 2, wn = wave & 3;          // 2 x 4 wave grid
  const int m0 = blockIdx.y * 256, n0 = blockIdx.x * 256;

  // staging decomposition: thread -> (row in half, 16B slot)
  const int sr = tid >> 2, sc = tid & 3;
  const int scol = (sc ^ (sr & 3) ^ ((sr >> 2) & 3)) * 8;   // swizzled src col (u16)
  const int cslot = (q ^ (l & 3) ^ ((l >> 2) & 3)) * 8;     // swizzled read slot (u16)
  const int wvoff = wave * 1024;                            // wave slice byte off in unit
  const int bl = (wn & 1) * 64 + l;                         // B row-in-half base

  const u16* aRow = Ap + (size_t)(m0 + sr) * lda + scol;
  const u16* bRow = Bp + (size_t)(n0 + sr) * K + scol;

#define STG_A(bb, h, kc, kb) \
  g2l16(aRow + (size_t)(h) * 128 * lda + (kb) + (kc) * 32, \
        (const char*)As + (bb) * 32768 + (h) * 16384 + (kc) * 8192 + wvoff)
#define STG_B(bb, h, kc, kb) \
  g2l16(bRow + (size_t)(h) * 128 * K + (kb) + (kc) * 32, \
        (const char*)Bs + (bb) * 32768 + (h) * 16384 + (kc) * 8192 + wvoff)

  bf16x8 af[4], bfr[4];
#define LOAD_A(rh, ks) { \
  af[0] = *(const bf16x8*)&As[abase + (ks) * 4096 + ((rh) * 64 +  0 + l) * 32 + cslot]; \
  af[1] = *(const bf16x8*)&As[abase + (ks) * 4096 + ((rh) * 64 + 16 + l) * 32 + cslot]; \
  af[2] = *(const bf16x8*)&As[abase + (ks) * 4096 + ((rh) * 64 + 32 + l) * 32 + cslot]; \
  af[3] = *(const bf16x8*)&As[abase + (ks) * 4096 + ((rh) * 64 + 48 + l) * 32 + cslot]; }
#define LOAD_B(ks) { \
  bfr[0] = *(const bf16x8*)&Bs[bbase + (ks) * 4096 + (bl +  0) * 32 + cslot]; \
  bfr[1] = *(const bf16x8*)&Bs[bbase + (ks) * 4096 + (bl + 16) * 32 + cslot]; \
  bfr[2] = *(const bf16x8*)&Bs[bbase + (ks) * 4096 + (bl + 32) * 32 + cslot]; \
  bfr[3] = *(const bf16x8*)&Bs[bbase + (ks) * 4096 + (bl + 48) * 32 + cslot]; }

  const f32x4 zero = {0.f, 0.f, 0.f, 0.f};
  f32x4 acc[8][4];
#pragma unroll
  for (int i = 0; i < 8; i++)
#pragma unroll
    for (int j = 0; j < 4; j++) acc[i][j] = zero;

#define MM(rh, i, j) acc[(rh) * 4 + (i)][j] = mfma_bf16(af[i], bfr[j], acc[(rh) * 4 + (i)][j]);
#define MFMA_PH(rh) { \
  MM(rh, 0, 0) MM(rh, 1, 0) MM(rh, 2, 0) MM(rh, 3, 0) \
  MM(rh, 0, 1) MM(rh, 1, 1) MM(rh, 2, 1) MM(rh, 3, 1) \
  MM(rh, 0, 2) MM(rh, 1, 2) MM(rh, 2, 2) MM(rh, 3, 2) \
  MM(rh, 0, 3) MM(rh, 1, 3) MM(rh, 2, 3) MM(rh, 3, 3) }

#define BAR   __builtin_amdgcn_s_barrier()
#define LGKM0 asm volatile("s_waitcnt lgkmcnt(0)" ::: "memory")
#define VM4   asm volatile("s_waitcnt vmcnt(4)" ::: "memory")
#define PRIO1 __builtin_amdgcn_s_setprio(1)
#define PRIO0 __builtin_amdgcn_s_setprio(0)

  const int NT = K >> 6;

  // prologue: stage tile 0 (k0 halves first, then k1), wait k0, enter loop
  STG_A(0, 0, 0, 0); STG_A(0, 1, 0, 0);
  STG_B(0, 0, 0, 0); STG_B(0, 1, 0, 0);
  STG_A(0, 0, 1, 0); STG_A(0, 1, 1, 0);
  STG_B(0, 0, 1, 0); STG_B(0, 1, 1, 0);
  VM4;
  BAR;

  for (int t = 0; t < NT - 1; ++t) {
    const int buf = t & 1, nb = buf ^ 1;
    const int abase = buf * 16384 + wm * 8192;
    const int bbase = buf * 16384 + (wn >> 1) * 8192;
    const int kb = (t + 1) * 64;
    // phase 0: rows 0-63, k0  | stage A-k0(t+1)
    LOAD_A(0, 0) LOAD_B(0)
    STG_A(nb, 0, 0, kb); STG_A(nb, 1, 0, kb);
    BAR; LGKM0; PRIO1; MFMA_PH(0) PRIO0; BAR;
    // phase 1: rows 64-127, k0 (reuse B frags) | stage B-k0(t+1) | vmcnt(4) -> k1(t) landed
    LOAD_A(1, 0)
    STG_B(nb, 0, 0, kb); STG_B(nb, 1, 0, kb);
    VM4;
    BAR; LGKM0; PRIO1; MFMA_PH(1) PRIO0; BAR;
    // phase 2: rows 0-63, k1 | stage A-k1(t+1)
    LOAD_A(0, 1) LOAD_B(1)
    STG_A(nb, 0, 1, kb); STG_A(nb, 1, 1, kb);
    BAR; LGKM0; PRIO1; MFMA_PH(0) PRIO0; BAR;
    // phase 3: rows 64-127, k1 | stage B-k1(t+1) | vmcnt(4) -> k0(t+1) landed
    LOAD_A(1, 1)
    STG_B(nb, 0, 1, kb); STG_B(nb, 1, 1, kb);
    VM4;
    BAR; LGKM0; PRIO1; MFMA_PH(1) PRIO0; BAR;
  }

  { // peeled last tile (no staging; drain k1 with vmcnt(0) at phase 1)
    const int buf = (NT - 1) & 1;
    const int abase = buf * 16384 + wm * 8192;
    const int bbase = buf * 16384 + (wn >> 1) * 8192;
    LOAD_A(0, 0) LOAD_B(0)
    BAR; LGKM0; PRIO1; MFMA_PH(0) PRIO0; BAR;
    LOAD_A(1, 0)
    asm volatile("s_waitcnt vmcnt(0)" ::: "memory");
    BAR; LGKM0; PRIO1; MFMA_PH(1) PRIO0; BAR;
    LOAD_A(0, 1) LOAD_B(1)
    BAR; LGKM0; PRIO1; MFMA_PH(0) PRIO0; BAR;
    LOAD_A(1, 1)
    BAR; LGKM0; PRIO1; MFMA_PH(1) PRIO0;
  }

#undef STG_A
#undef STG_B
#undef LOAD_A
#undef LOAD_B
#undef MM
#undef MFMA_PH
#undef BAR
#undef LGKM0
#undef VM4
#undef PRIO1
#undef PRIO0

  // ---------------- epilogue
  float mk[8][4];
  if constexpr (HAS_MASK) {
#pragma unroll
    for (int i = 0; i < 8; i++) {
      const int row = m0 + wm * 128 + i * 16 + q * 4;
#pragma unroll
      for (int r = 0; r < 4; r++) mk[i][r] = rowmask[row + r];
    }
  }
#pragma unroll
  for (int j = 0; j < 4; j++) {
    const int col = n0 + wn * 64 + j * 16 + l;
    const float bv = bias[col];
    if constexpr (OUT_MODE == 2) {
      if (col < 1024) {
#pragma unroll
        for (int i = 0; i < 8; i++) {
          const int row = m0 + wm * 128 + i * 16 + q * 4;
#pragma unroll
          for (int r = 0; r < 4; r++) {
            float v = (acc[i][j][r] + bv) * mk[i][r];
            ((u16*)Cp)[(size_t)(row + r) * 1024 + col] = f2bf(v);
          }
        }
      } else {
        const int cv = col - 1024, hh = cv >> 7, d = cv & 127;
#pragma unroll
        for (int i = 0; i < 8; i++) {
          const int m = m0 + wm * 128 + i * 16 + q * 4;
          u16x4 o;
#pragma unroll
          for (int r = 0; r < 4; r++) o[r] = f2bf((acc[i][j][r] + bv) * mk[i][r]);
          *(u16x4*)&C2p[((size_t)((m >> 10) * 8 + hh) * 128 + d) * 1024 + (m & 1023)] = o;
        }
      }
    } else {
#pragma unroll
      for (int i = 0; i < 8; i++) {
        const int row = m0 + wm * 128 + i * 16 + q * 4;
#pragma unroll
        for (int r = 0; r < 4; r++) {
          float v = acc[i][j][r] + bv;
          if constexpr (HAS_MASK) v *= mk[i][r];
          const size_t off = (size_t)(row + r) * ldc + col;
          if constexpr (OUT_MODE == 1) ((u16*)Cp)[off] = f2bf(v);
          else                         ((float*)Cp)[off] = v;
        }
      }
    }
  }
}

// ---------------------------------------------------------------- flash attention
// grid (T/128, H, B), 256 threads = 4 waves; wave owns 32 q-rows (two 16-row tiles)
__global__ __launch_bounds__(256) void attn_k(
    const u16* __restrict__ st,    // keys [B*S][1024]
    const u16* __restrict__ vt,    // [B*H][128][1024] (V^T)
    const u16* __restrict__ qb,    // tgt_trans [B*T][1024]
    const float* __restrict__ smask,
    u16* __restrict__ cat)         // [B*T][2048], writes cols 1024..2047
{
  const int tq = blockIdx.x, h = blockIdx.y, b = blockIdx.z;
  const int tid = threadIdx.x, wave = tid >> 6, lane = tid & 63;
  const int l = lane & 15, q = lane >> 4;

  __shared__ u16 Ks[64 * 128];     // [s][d], chunk-swizzled (16 chunks): pos = c ^ (row&15)
  __shared__ u16 Vs[128 * 64];     // [d][s], chunk-swizzled (8 chunks):  pos = c ^ (row&7)
  __shared__ u16 Pl[4][32 * 72];   // per-wave P scratch (padded rows)

  const int qr0 = b * 512 + tq * 128 + wave * 32;
  bf16x8 aQ[2][4];
#pragma unroll
  for (int m = 0; m < 2; m++)
#pragma unroll
    for (int kk = 0; kk < 4; kk++)
      aQ[m][kk] = *(const bf16x8*)&qb[(size_t)(qr0 + m * 16 + l) * 1024 + h * 128 + kk * 32 + q * 8];

  const f32x4 zero = {0.f, 0.f, 0.f, 0.f};
  f32x4 o[2][8];
#pragma unroll
  for (int m = 0; m < 2; m++)
#pragma unroll
    for (int n = 0; n < 8; n++) o[m][n] = zero;
  float m_i[2][4], l_i[2][4];
#pragma unroll
  for (int m = 0; m < 2; m++)
#pragma unroll
    for (int r = 0; r < 4; r++) { m_i[m][r] = -3e38f; l_i[m][r] = 0.f; }

  const u16* kbase = st + (size_t)b * 1024 * 1024 + h * 128;
  const u16* vbase = vt + (size_t)(b * 8 + h) * 128 * 1024;
  const float* mbase = smask + b * 1024;
  const float scale = 0.08838834764831845f;  // 1/sqrt(128)

  const int krow = lane >> 4, kcp = lane & 15;
  const int vrow = lane >> 3, vcp = lane & 7;

  for (int s0 = 0; s0 < 1024; s0 += 64) {
    __syncthreads();
#pragma unroll
    for (int j = 0; j < 4; j++) {
      const int i = wave * 4 + j;
      const int kr = i * 4 + krow;
      g2l16(kbase + (size_t)(s0 + kr) * 1024 + (kcp ^ (kr & 15)) * 8, (const char*)Ks + i * 1024);
      const int vr = i * 8 + vrow;
      g2l16(vbase + (size_t)vr * 1024 + s0 + (vcp ^ (vr & 7)) * 8,    (const char*)Vs + i * 1024);
    }
    __syncthreads();

    // QK^T — K-frags shared across both row-tiles
    f32x4 s[2][4];
#pragma unroll
    for (int m = 0; m < 2; m++)
#pragma unroll
      for (int nt = 0; nt < 4; nt++) s[m][nt] = zero;
#pragma unroll
    for (int kk = 0; kk < 4; kk++) {
#pragma unroll
      for (int nt = 0; nt < 4; nt++) {
        bf16x8 bk = *(const bf16x8*)&Ks[(nt * 16 + l) * 128 + ((kk * 4 + q) ^ l) * 8];
        s[0][nt] = mfma_bf16(aQ[0][kk], bk, s[0][nt]);
        s[1][nt] = mfma_bf16(aQ[1][kk], bk, s[1][nt]);
      }
    }

    float msk[4];
#pragma unroll
    for (int nt = 0; nt < 4; nt++) msk[nt] = mbase[s0 + nt * 16 + l];

#pragma unroll
    for (int m = 0; m < 2; m++) {
      float tm[4] = {-3e38f, -3e38f, -3e38f, -3e38f};
#pragma unroll
      for (int nt = 0; nt < 4; nt++) {
#pragma unroll
        for (int r = 0; r < 4; r++) {
          float v = s[m][nt][r] * scale;
          v = (msk[nt] == 0.f) ? -3e38f : v;
          s[m][nt][r] = v;
          tm[r] = fmaxf(tm[r], v);
        }
      }
#pragma unroll
      for (int off = 1; off < 16; off <<= 1)
#pragma unroll
        for (int r = 0; r < 4; r++) tm[r] = fmaxf(tm[r], __shfl_xor(tm[r], off));

      float alpha[4], ts[4];
#pragma unroll
      for (int r = 0; r < 4; r++) {
        const float mn = fmaxf(m_i[m][r], tm[r]);
        alpha[r] = __expf(m_i[m][r] - mn);
        m_i[m][r] = mn;
        ts[r] = 0.f;
      }
#pragma unroll
      for (int nt = 0; nt < 4; nt++) {
#pragma unroll
        for (int r = 0; r < 4; r++) {
          const float e = (msk[nt] == 0.f) ? 0.f : __expf(s[m][nt][r] - m_i[m][r]);
          ts[r] += e;
          Pl[wave][(m * 16 + q * 4 + r) * 72 + nt * 16 + l] = f2bf(e);
        }
      }
#pragma unroll
      for (int off = 1; off < 16; off <<= 1)
#pragma unroll
        for (int r = 0; r < 4; r++) ts[r] += __shfl_xor(ts[r], off);
#pragma unroll
      for (int r = 0; r < 4; r++) l_i[m][r] = l_i[m][r] * alpha[r] + ts[r];
#pragma unroll
      for (int n = 0; n < 8; n++)
#pragma unroll
        for (int r = 0; r < 4; r++) o[m][n][r] *= alpha[r];
    }

    asm volatile("s_waitcnt lgkmcnt(0)" ::: "memory");  // Pl writes -> reads (wave-local)

    // PV
#pragma unroll
    for (int k2 = 0; k2 < 2; k2++) {
      bf16x8 ap0 = *(const bf16x8*)&Pl[wave][l * 72 + k2 * 32 + q * 8];
      bf16x8 ap1 = *(const bf16x8*)&Pl[wave][(16 + l) * 72 + k2 * 32 + q * 8];
#pragma unroll
      for (int n = 0; n < 8; n++) {
        bf16x8 bv = *(const bf16x8*)&Vs[(n * 16 + l) * 64 + ((k2 * 4 + q) ^ (l & 7)) * 8];
        o[0][n] = mfma_bf16(ap0, bv, o[0][n]);
        o[1][n] = mfma_bf16(ap1, bv, o[1][n]);
      }
    }
  }

#pragma unroll
  for (int m = 0; m < 2; m++) {
    float inv[4];
#pragma unroll
    for (int r = 0; r < 4; r++) inv[r] = 1.f / l_i[m][r];
    u16* ob = cat + (size_t)(qr0 + m * 16 + q * 4) * 2048 + 1024 + h * 128 + l;
#pragma unroll
    for (int n = 0; n < 8; n++)
#pragma unroll
      for (int r = 0; r < 4; r++)
        ob[(size_t)r * 2048 + n * 16] = f2bf(o[m][n][r] * inv[r]);
  }
}

// ---------------------------------------------------------------- launcher
extern "C" void kernel_launch(void* const* d_in, const int* in_sizes, int n_in,
                              void* d_out, int out_size, void* d_ws, size_t ws_size,
                              hipStream_t stream)
{
  (void)in_sizes; (void)n_in; (void)out_size; (void)ws_size;
  const float* src      = (const float*)d_in[0];
  const float* tgtf     = (const float*)d_in[1];
  const float* src_mask = (const float*)d_in[2];
  const float* tgt_mask = (const float*)d_in[3];
  const float* v_src = (const float*)d_in[4];
  const float* g_src = (const float*)d_in[5];
  const float* b_src = (const float*)d_in[6];
  const float* v_tgt = (const float*)d_in[7];
  const float* g_tgt = (const float*)d_in[8];
  const float* b_tgt = (const float*)d_in[9];
  const float* v_out = (const float*)d_in[10];
  const float* g_out = (const float*)d_in[11];
  const float* b_out = (const float*)d_in[12];

  char* w = (char*)d_ws;
  float* sumsq = (float*)w;
  size_t off = 256;
  u16* w_src = (u16*)(w + off); off += (size_t)2048 * 1024 * 2;
  u16* w_tgt = (u16*)(w + off); off += (size_t)1024 * 1024 * 2;
  u16* w_out = (u16*)(w + off); off += (size_t)1024 * 2048 * 2;
  u16* st    = (u16*)(w + off); off += (size_t)32768 * 1024 * 2;     // keys only
  u16* qb    = (u16*)(w + off); off += (size_t)16384 * 1024 * 2;     // tgt_trans
  u16* vt    = (u16*)(w + off); off += (size_t)256 * 128 * 1024 * 2; // V^T
  u16* cat   = (u16*)(w + off); off += (size_t)16384 * 2048 * 2;     // [tgt | tgt_update]
  u16* srcb  = cat;  // src bf16 alias (consumed by gemm1 before catleft/attn overwrite)

  hipMemsetAsync(sumsq, 0, 256, stream);
  sumsq3_k<<<384, 256, 0, stream>>>(v_src, v_tgt, v_out, sumsq);
  wconv3_k<<<5120, 256, 0, stream>>>(v_src, v_tgt, v_out, g_src, g_tgt, g_out,
                                     sumsq, w_src, w_tgt, w_out);
  cvt_k<<<32768, 256, 0, stream>>>(src, srcb);

  // src_trans: keys -> st, values -> vt (transposed), both masked  [32768 x 2048]
  gemm_bt256<2, true><<<dim3(8, 128), 512, 0, stream>>>(
      srcb, w_src, b_src, src_mask, (void*)st, vt, 1024, 1024, 0);
  catleft_k<<<16384, 256, 0, stream>>>(tgtf, cat);
  // tgt_trans = (tgt @ W_tgt^T + b_tgt) * tgt_mask   [16384 x 1024]
  gemm_bt256<1, true><<<dim3(4, 64), 512, 0, stream>>>(
      cat, w_tgt, b_tgt, tgt_mask, (void*)qb, nullptr, 2048, 2048, 1024);
  // flash attention -> cat[:, 1024:]
  attn_k<<<dim3(4, 8, 32), 256, 0, stream>>>(st, vt, qb, src_mask, cat);
  // out = cat @ W_out^T + b_out   [16384 x 1024] f32
  gemm_bt256<0, false><<<dim3(4, 64), 512, 0, stream>>>(
      cat, w_out, b_out, nullptr, d_out, nullptr, 2048, 2048, 1024);
}

// Round 2
// 731.150 us; speedup vs baseline: 1.1652x; 1.1409x over previous
//
#include <hip/hip_runtime.h>
#include <hip/hip_bf16.h>
#include <math.h>

#define DEVI __device__ __forceinline__

typedef unsigned short u16;
typedef __attribute__((ext_vector_type(8))) __bf16 bf16x8;
typedef __attribute__((ext_vector_type(4))) float f32x4;
typedef __attribute__((ext_vector_type(8))) unsigned short u16x8;
typedef __attribute__((ext_vector_type(4))) unsigned short u16x4;

typedef __attribute__((address_space(1))) void gvoid;
typedef __attribute__((address_space(3))) void lvoid;

DEVI u16 f2bf(float f) {
  unsigned u = __builtin_bit_cast(unsigned, f);
  u += 0x7fffu + ((u >> 16) & 1u);   // RNE
  return (u16)(u >> 16);
}

DEVI f32x4 mfma_bf16(bf16x8 a, bf16x8 b, f32x4 c) {
  return __builtin_amdgcn_mfma_f32_16x16x32_bf16(a, b, c, 0, 0, 0);
}

DEVI void g2l16(const void* g, const void* l) {
  __builtin_amdgcn_global_load_lds((gvoid*)(size_t)g,
                                   (lvoid*)(unsigned)(size_t)l, 16, 0, 0);
}

// ---------------------------------------------------------------- fused small kernels
__global__ void sumsq3_k(const float* __restrict__ v0, const float* __restrict__ v1,
                         const float* __restrict__ v2, float* __restrict__ out)
{
  const int seg = blockIdx.x >> 7, wb = blockIdx.x & 127;
  const float* v = seg == 0 ? v0 : (seg == 1 ? v1 : v2);
  const int n4 = (seg == 1) ? 262144 : 524288;
  float s = 0.f;
  for (int i = wb * 256 + threadIdx.x; i < n4; i += 128 * 256) {
    f32x4 x = *(const f32x4*)(v + (size_t)i * 4);
    s += x.x * x.x + x.y * x.y + x.z * x.z + x.w * x.w;
  }
#pragma unroll
  for (int off = 32; off > 0; off >>= 1) s += __shfl_down(s, off);
  __shared__ float part[4];
  if ((threadIdx.x & 63) == 0) part[threadIdx.x >> 6] = s;
  __syncthreads();
  if (threadIdx.x == 0) atomicAdd(out + seg, part[0] + part[1] + part[2] + part[3]);
}

__global__ void wconv3_k(const float* __restrict__ v0, const float* __restrict__ v1,
                         const float* __restrict__ v2,
                         const float* __restrict__ g0, const float* __restrict__ g1,
                         const float* __restrict__ g2,
                         const float* __restrict__ ss,
                         u16* __restrict__ w0, u16* __restrict__ w1, u16* __restrict__ w2)
{
  const int i = blockIdx.x * 256 + threadIdx.x;  // f32x4 index over 1310720
  int seg, base;
  const float* v; u16* w;
  if (i < 524288)      { seg = 0; base = 0;      v = v0; w = w0; }
  else if (i < 786432) { seg = 1; base = 524288; v = v1; w = w1; }
  else                 { seg = 2; base = 786432; v = v2; w = w2; }
  const float* g = seg == 0 ? g0 : (seg == 1 ? g1 : g2);
  const float sc = g[0] / sqrtf(ss[seg]);
  const int j = i - base;
  f32x4 x = *(const f32x4*)(v + (size_t)j * 4);
  u16x4 o;
  o[0] = f2bf(x.x * sc); o[1] = f2bf(x.y * sc);
  o[2] = f2bf(x.z * sc); o[3] = f2bf(x.w * sc);
  *(u16x4*)(w + (size_t)j * 4) = o;
}

__global__ void cvt_k(const float* __restrict__ x, u16* __restrict__ y)
{
  const size_t i = (size_t)(blockIdx.x * blockDim.x + threadIdx.x) * 4;
  f32x4 v = *(const f32x4*)(x + i);
  u16x4 o;
  o[0] = f2bf(v.x); o[1] = f2bf(v.y); o[2] = f2bf(v.z); o[3] = f2bf(v.w);
  *(u16x4*)(y + i) = o;
}

__global__ void catleft_k(const float* __restrict__ tgt, u16* __restrict__ cat)
{
  const size_t e = (size_t)(blockIdx.x * blockDim.x + threadIdx.x) * 4;
  const int row = (int)(e >> 10), c = (int)(e & 1023);
  f32x4 x = *(const f32x4*)(tgt + e);
  u16x4 o;
  o[0] = f2bf(x.x); o[1] = f2bf(x.y); o[2] = f2bf(x.z); o[3] = f2bf(x.w);
  *(u16x4*)&cat[(size_t)row * 2048 + c] = o;
}

// ---------------------------------------------------------------- GEMM 256x256, 8-phase
// C = A @ B^T + bias. A [M][lda], B [N][K] bf16. BM=BN=256, BK=64, 512 thr (8 waves 2x4).
// LDS: SH = [As: 2buf x 2half x 2kplane x 128r x 32u16][Bs: same], st_16x32 swizzle:
//   16B slot s of row r holds global chunk (s ^ ((r>>2)&2))  [m201-verified pattern].
// 4 phases/K-tile: {ds_read frags | stage 1 unit of tile t+1 | barrier | lgkmcnt(0) |
//   setprio(1) 16 MFMA setprio(0) | barrier}. vmcnt(4) at phases 1,3 (counted).
// XCD-chunked block swizzle (bijective, nwg % 8 == 0).
// OUT_MODE: 0 = f32 (ldc), 1 = bf16 (ldc), 2 = split: cols<1024 -> st[.][1024],
//           cols>=1024 -> LDS-gathered transpose into vt[b*8+h][128][1024].
template<int OUT_MODE, bool HAS_MASK>
__global__ __launch_bounds__(512, 2) void gemm_bt256(
    const u16* __restrict__ Ap, const u16* __restrict__ Bp,
    const float* __restrict__ bias, const float* __restrict__ rowmask,
    void* __restrict__ Cp, u16* __restrict__ C2p, int K, int lda, int ldc)
{
  __shared__ __align__(16) u16 SH[65536];   // 128 KiB
  const int tid = threadIdx.x;
  const int wave = tid >> 6, lane = tid & 63;
  const int l = lane & 15, q = lane >> 4;
  const int wm = wave >> 2, wn = wave & 3;          // 2 x 4 wave grid

  // XCD-chunked bijective swizzle: XCD k gets a contiguous lin-range
  const int nbx = gridDim.x;
  const int wg0 = blockIdx.y * nbx + blockIdx.x;
  const int nwg = nbx * (int)gridDim.y;             // multiple of 8
  const int lin = (wg0 & 7) * (nwg >> 3) + (wg0 >> 3);
  const int bx = lin % nbx, by = lin / nbx;
  const int m0 = by * 256, n0 = bx * 256;

  // staging decomposition: thread -> (row in half, 16B slot), st_16x32 swizzle
  const int sr = tid >> 2, sc = tid & 3;
  const int scol = (sc ^ ((sr >> 2) & 2)) * 8;      // swizzled src col (u16)
  const int cslot = (q ^ ((l >> 2) & 2)) * 8;       // swizzled read slot (u16)
  const int wvoff = wave * 1024;                    // wave slice byte off in unit
  const int bl = (wn & 1) * 64 + l;                 // B row-in-half base

  const u16* aRow = Ap + (size_t)(m0 + sr) * lda + scol;
  const u16* bRow = Bp + (size_t)(n0 + sr) * K + scol;

#define STG_A(bb, h, kc, kb) \
  g2l16(aRow + (size_t)(h) * 128 * lda + (kb) + (kc) * 32, \
        (const char*)SH + (bb) * 32768 + (h) * 16384 + (kc) * 8192 + wvoff)
#define STG_B(bb, h, kc, kb) \
  g2l16(bRow + (size_t)(h) * 128 * K + (kb) + (kc) * 32, \
        (const char*)SH + 65536 + (bb) * 32768 + (h) * 16384 + (kc) * 8192 + wvoff)

  bf16x8 af[4], bfr[4];
#define LOAD_A(rh, ks) { \
  af[0] = *(const bf16x8*)&SH[abase + (ks) * 4096 + ((rh) * 64 +  0 + l) * 32 + cslot]; \
  af[1] = *(const bf16x8*)&SH[abase + (ks) * 4096 + ((rh) * 64 + 16 + l) * 32 + cslot]; \
  af[2] = *(const bf16x8*)&SH[abase + (ks) * 4096 + ((rh) * 64 + 32 + l) * 32 + cslot]; \
  af[3] = *(const bf16x8*)&SH[abase + (ks) * 4096 + ((rh) * 64 + 48 + l) * 32 + cslot]; }
#define LOAD_B(ks) { \
  bfr[0] = *(const bf16x8*)&SH[bbase + (ks) * 4096 + (bl +  0) * 32 + cslot]; \
  bfr[1] = *(const bf16x8*)&SH[bbase + (ks) * 4096 + (bl + 16) * 32 + cslot]; \
  bfr[2] = *(const bf16x8*)&SH[bbase + (ks) * 4096 + (bl + 32) * 32 + cslot]; \
  bfr[3] = *(const bf16x8*)&SH[bbase + (ks) * 4096 + (bl + 48) * 32 + cslot]; }

  const f32x4 zero = {0.f, 0.f, 0.f, 0.f};
  f32x4 acc[8][4];
#pragma unroll
  for (int i = 0; i < 8; i++)
#pragma unroll
    for (int j = 0; j < 4; j++) acc[i][j] = zero;

#define MM(rh, i, j) acc[(rh) * 4 + (i)][j] = mfma_bf16(af[i], bfr[j], acc[(rh) * 4 + (i)][j]);
#define MFMA_PH(rh) { \
  MM(rh, 0, 0) MM(rh, 1, 0) MM(rh, 2, 0) MM(rh, 3, 0) \
  MM(rh, 0, 1) MM(rh, 1, 1) MM(rh, 2, 1) MM(rh, 3, 1) \
  MM(rh, 0, 2) MM(rh, 1, 2) MM(rh, 2, 2) MM(rh, 3, 2) \
  MM(rh, 0, 3) MM(rh, 1, 3) MM(rh, 2, 3) MM(rh, 3, 3) }

#define BAR   __builtin_amdgcn_s_barrier()
#define LGKM0 asm volatile("s_waitcnt lgkmcnt(0)" ::: "memory")
#define VM4   asm volatile("s_waitcnt vmcnt(4)" ::: "memory")
#define PRIO1 __builtin_amdgcn_s_setprio(1)
#define PRIO0 __builtin_amdgcn_s_setprio(0)

  const int NT = K >> 6;

  // prologue: stage tile 0 (k0 halves first, then k1), wait k0, enter loop
  STG_A(0, 0, 0, 0); STG_A(0, 1, 0, 0);
  STG_B(0, 0, 0, 0); STG_B(0, 1, 0, 0);
  STG_A(0, 0, 1, 0); STG_A(0, 1, 1, 0);
  STG_B(0, 0, 1, 0); STG_B(0, 1, 1, 0);
  VM4;
  BAR;

  for (int t = 0; t < NT - 1; ++t) {
    const int buf = t & 1, nb = buf ^ 1;
    const int abase = buf * 16384 + wm * 8192;
    const int bbase = 32768 + buf * 16384 + (wn >> 1) * 8192;
    const int kb = (t + 1) * 64;
    // phase 0: rows 0-63, k0  | stage A-k0(t+1)
    LOAD_A(0, 0) LOAD_B(0)
    STG_A(nb, 0, 0, kb); STG_A(nb, 1, 0, kb);
    BAR; LGKM0; PRIO1; MFMA_PH(0) PRIO0; BAR;
    // phase 1: rows 64-127, k0 (reuse B frags) | stage B-k0(t+1) | vmcnt(4) -> k1(t) landed
    LOAD_A(1, 0)
    STG_B(nb, 0, 0, kb); STG_B(nb, 1, 0, kb);
    VM4;
    BAR; LGKM0; PRIO1; MFMA_PH(1) PRIO0; BAR;
    // phase 2: rows 0-63, k1 | stage A-k1(t+1)
    LOAD_A(0, 1) LOAD_B(1)
    STG_A(nb, 0, 1, kb); STG_A(nb, 1, 1, kb);
    BAR; LGKM0; PRIO1; MFMA_PH(0) PRIO0; BAR;
    // phase 3: rows 64-127, k1 | stage B-k1(t+1) | vmcnt(4) -> k0(t+1) landed
    LOAD_A(1, 1)
    STG_B(nb, 0, 1, kb); STG_B(nb, 1, 1, kb);
    VM4;
    BAR; LGKM0; PRIO1; MFMA_PH(1) PRIO0; BAR;
  }

  { // peeled last tile (no staging; drain k1 with vmcnt(0) at phase 1)
    const int buf = (NT - 1) & 1;
    const int abase = buf * 16384 + wm * 8192;
    const int bbase = 32768 + buf * 16384 + (wn >> 1) * 8192;
    LOAD_A(0, 0) LOAD_B(0)
    BAR; LGKM0; PRIO1; MFMA_PH(0) PRIO0; BAR;
    LOAD_A(1, 0)
    asm volatile("s_waitcnt vmcnt(0)" ::: "memory");
    BAR; LGKM0; PRIO1; MFMA_PH(1) PRIO0; BAR;
    LOAD_A(0, 1) LOAD_B(1)
    BAR; LGKM0; PRIO1; MFMA_PH(0) PRIO0; BAR;
    LOAD_A(1, 1)
    BAR; LGKM0; PRIO1; MFMA_PH(1) PRIO0;
  }

#undef STG_A
#undef STG_B
#undef LOAD_A
#undef LOAD_B
#undef MM
#undef MFMA_PH
#undef BAR
#undef LGKM0
#undef VM4
#undef PRIO1
#undef PRIO0

  // ---------------- epilogue
  float mk[8][4];
  if constexpr (HAS_MASK) {
#pragma unroll
    for (int i = 0; i < 8; i++) {
      const int row = m0 + wm * 128 + i * 16 + q * 4;
#pragma unroll
      for (int r = 0; r < 4; r++) mk[i][r] = rowmask[row + r];
    }
  }

  if constexpr (OUT_MODE == 2) {
    if (n0 >= 1024) {
      // ---- vt branch: gather block slab [256 n][256 m u16] in LDS, write coalesced.
      asm volatile("s_waitcnt lgkmcnt(0)" ::: "memory");  // own loop ds_reads done
      __syncthreads();                                     // everyone done with SH
#pragma unroll
      for (int j = 0; j < 4; j++) {
        const int nl = wn * 64 + j * 16 + l;
        const float bv = bias[n0 + nl];
#pragma unroll
        for (int i = 0; i < 8; i++) {
          u16x4 o;
#pragma unroll
          for (int r = 0; r < 4; r++) o[r] = f2bf((acc[i][j][r] + bv) * mk[i][r]);
          const int chunk = wm * 16 + i * 2 + (q >> 1);          // 16B chunk of m-span
          *(u16x4*)&SH[nl * 256 + ((chunk ^ (nl & 31)) * 8) + (q & 1) * 4] = o;
        }
      }
      __syncthreads();
      // writer: thread t -> row nl2 = t>>1, half = t&1; 256B contiguous per thread
      const int nl2 = tid >> 1, half = tid & 1;
      const int cv = n0 + nl2 - 1024, hh = cv >> 7, d = cv & 127;
      u16* dst = C2p + ((size_t)((m0 >> 10) * 8 + hh) * 128 + d) * 1024
               + (m0 & 1023) + half * 128;
#pragma unroll
      for (int c = 0; c < 16; c++) {
        const int ch = half * 16 + c;
        *(u16x8*)&dst[c * 8] = *(const u16x8*)&SH[nl2 * 256 + ((ch ^ (nl2 & 31)) * 8)];
      }
    } else {
      // ---- st branch (col < 1024): direct store, coalesces across q
#pragma unroll
      for (int j = 0; j < 4; j++) {
        const int col = n0 + wn * 64 + j * 16 + l;
        const float bv = bias[col];
#pragma unroll
        for (int i = 0; i < 8; i++) {
          const int row = m0 + wm * 128 + i * 16 + q * 4;
#pragma unroll
          for (int r = 0; r < 4; r++) {
            float v = (acc[i][j][r] + bv) * mk[i][r];
            ((u16*)Cp)[(size_t)(row + r) * 1024 + col] = f2bf(v);
          }
        }
      }
    }
  } else {
#pragma unroll
    for (int j = 0; j < 4; j++) {
      const int col = n0 + wn * 64 + j * 16 + l;
      const float bv = bias[col];
#pragma unroll
      for (int i = 0; i < 8; i++) {
        const int row = m0 + wm * 128 + i * 16 + q * 4;
#pragma unroll
        for (int r = 0; r < 4; r++) {
          float v = acc[i][j][r] + bv;
          if constexpr (HAS_MASK) v *= mk[i][r];
          const size_t off = (size_t)(row + r) * ldc + col;
          if constexpr (OUT_MODE == 1) ((u16*)Cp)[off] = f2bf(v);
          else                         ((float*)Cp)[off] = v;
        }
      }
    }
  }
}

// ---------------------------------------------------------------- flash attention
// grid (T/128, H, B), 256 threads = 4 waves; wave owns 32 q-rows (two 16-row tiles)
__global__ __launch_bounds__(256) void attn_k(
    const u16* __restrict__ st,    // keys [B*S][1024]
    const u16* __restrict__ vt,    // [B*H][128][1024] (V^T)
    const u16* __restrict__ qb,    // tgt_trans [B*T][1024]
    const float* __restrict__ smask,
    u16* __restrict__ cat)         // [B*T][2048], writes cols 1024..2047
{
  const int tq = blockIdx.x, h = blockIdx.y, b = blockIdx.z;
  const int tid = threadIdx.x, wave = tid >> 6, lane = tid & 63;
  const int l = lane & 15, q = lane >> 4;

  __shared__ u16 Ks[64 * 128];     // [s][d], chunk-swizzled (16 chunks): pos = c ^ (row&15)
  __shared__ u16 Vs[128 * 64];     // [d][s], chunk-swizzled (8 chunks):  pos = c ^ (row&7)
  __shared__ u16 Pl[4][32 * 72];   // per-wave P scratch (padded rows)

  const int qr0 = b * 512 + tq * 128 + wave * 32;
  bf16x8 aQ[2][4];
#pragma unroll
  for (int m = 0; m < 2; m++)
#pragma unroll
    for (int kk = 0; kk < 4; kk++)
      aQ[m][kk] = *(const bf16x8*)&qb[(size_t)(qr0 + m * 16 + l) * 1024 + h * 128 + kk * 32 + q * 8];

  const f32x4 zero = {0.f, 0.f, 0.f, 0.f};
  f32x4 o[2][8];
#pragma unroll
  for (int m = 0; m < 2; m++)
#pragma unroll
    for (int n = 0; n < 8; n++) o[m][n] = zero;
  float m_i[2][4], l_i[2][4];
#pragma unroll
  for (int m = 0; m < 2; m++)
#pragma unroll
    for (int r = 0; r < 4; r++) { m_i[m][r] = -3e38f; l_i[m][r] = 0.f; }

  const u16* kbase = st + (size_t)b * 1024 * 1024 + h * 128;
  const u16* vbase = vt + (size_t)(b * 8 + h) * 128 * 1024;
  const float* mbase = smask + b * 1024;
  const float scale = 0.08838834764831845f;  // 1/sqrt(128)

  const int krow = lane >> 4, kcp = lane & 15;
  const int vrow = lane >> 3, vcp = lane & 7;

  for (int s0 = 0; s0 < 1024; s0 += 64) {
    __syncthreads();
#pragma unroll
    for (int j = 0; j < 4; j++) {
      const int i = wave * 4 + j;
      const int kr = i * 4 + krow;
      g2l16(kbase + (size_t)(s0 + kr) * 1024 + (kcp ^ (kr & 15)) * 8, (const char*)Ks + i * 1024);
      const int vr = i * 8 + vrow;
      g2l16(vbase + (size_t)vr * 1024 + s0 + (vcp ^ (vr & 7)) * 8,    (const char*)Vs + i * 1024);
    }
    __syncthreads();

    // QK^T — K-frags shared across both row-tiles
    f32x4 s[2][4];
#pragma unroll
    for (int m = 0; m < 2; m++)
#pragma unroll
      for (int nt = 0; nt < 4; nt++) s[m][nt] = zero;
#pragma unroll
    for (int kk = 0; kk < 4; kk++) {
#pragma unroll
      for (int nt = 0; nt < 4; nt++) {
        bf16x8 bk = *(const bf16x8*)&Ks[(nt * 16 + l) * 128 + ((kk * 4 + q) ^ l) * 8];
        s[0][nt] = mfma_bf16(aQ[0][kk], bk, s[0][nt]);
        s[1][nt] = mfma_bf16(aQ[1][kk], bk, s[1][nt]);
      }
    }

    float msk[4];
#pragma unroll
    for (int nt = 0; nt < 4; nt++) msk[nt] = mbase[s0 + nt * 16 + l];

#pragma unroll
    for (int m = 0; m < 2; m++) {
      float tm[4] = {-3e38f, -3e38f, -3e38f, -3e38f};
#pragma unroll
      for (int nt = 0; nt < 4; nt++) {
#pragma unroll
        for (int r = 0; r < 4; r++) {
          float v = s[m][nt][r] * scale;
          v = (msk[nt] == 0.f) ? -3e38f : v;
          s[m][nt][r] = v;
          tm[r] = fmaxf(tm[r], v);
        }
      }
#pragma unroll
      for (int off = 1; off < 16; off <<= 1)
#pragma unroll
        for (int r = 0; r < 4; r++) tm[r] = fmaxf(tm[r], __shfl_xor(tm[r], off));

      float alpha[4], ts[4];
#pragma unroll
      for (int r = 0; r < 4; r++) {
        const float mn = fmaxf(m_i[m][r], tm[r]);
        alpha[r] = __expf(m_i[m][r] - mn);
        m_i[m][r] = mn;
        ts[r] = 0.f;
      }
#pragma unroll
      for (int nt = 0; nt < 4; nt++) {
#pragma unroll
        for (int r = 0; r < 4; r++) {
          const float e = (msk[nt] == 0.f) ? 0.f : __expf(s[m][nt][r] - m_i[m][r]);
          ts[r] += e;
          Pl[wave][(m * 16 + q * 4 + r) * 72 + nt * 16 + l] = f2bf(e);
        }
      }
#pragma unroll
      for (int off = 1; off < 16; off <<= 1)
#pragma unroll
        for (int r = 0; r < 4; r++) ts[r] += __shfl_xor(ts[r], off);
#pragma unroll
      for (int r = 0; r < 4; r++) l_i[m][r] = l_i[m][r] * alpha[r] + ts[r];
#pragma unroll
      for (int n = 0; n < 8; n++)
#pragma unroll
        for (int r = 0; r < 4; r++) o[m][n][r] *= alpha[r];
    }

    asm volatile("s_waitcnt lgkmcnt(0)" ::: "memory");  // Pl writes -> reads (wave-local)

    // PV
#pragma unroll
    for (int k2 = 0; k2 < 2; k2++) {
      bf16x8 ap0 = *(const bf16x8*)&Pl[wave][l * 72 + k2 * 32 + q * 8];
      bf16x8 ap1 = *(const bf16x8*)&Pl[wave][(16 + l) * 72 + k2 * 32 + q * 8];
#pragma unroll
      for (int n = 0; n < 8; n++) {
        bf16x8 bv = *(const bf16x8*)&Vs[(n * 16 + l) * 64 + ((k2 * 4 + q) ^ (l & 7)) * 8];
        o[0][n] = mfma_bf16(ap0, bv, o[0][n]);
        o[1][n] = mfma_bf16(ap1, bv, o[1][n]);
      }
    }
  }

#pragma unroll
  for (int m = 0; m < 2; m++) {
    float inv[4];
#pragma unroll
    for (int r = 0; r < 4; r++) inv[r] = 1.f / l_i[m][r];
    u16* ob = cat + (size_t)(qr0 + m * 16 + q * 4) * 2048 + 1024 + h * 128 + l;
#pragma unroll
    for (int n = 0; n < 8; n++)
#pragma unroll
      for (int r = 0; r < 4; r++)
        ob[(size_t)r * 2048 + n * 16] = f2bf(o[m][n][r] * inv[r]);
  }
}

// ---------------------------------------------------------------- launcher
extern "C" void kernel_launch(void* const* d_in, const int* in_sizes, int n_in,
                              void* d_out, int out_size, void* d_ws, size_t ws_size,
                              hipStream_t stream)
{
  (void)in_sizes; (void)n_in; (void)out_size; (void)ws_size;
  const float* src      = (const float*)d_in[0];
  const float* tgtf     = (const float*)d_in[1];
  const float* src_mask = (const float*)d_in[2];
  const float* tgt_mask = (const float*)d_in[3];
  const float* v_src = (const float*)d_in[4];
  const float* g_src = (const float*)d_in[5];
  const float* b_src = (const float*)d_in[6];
  const float* v_tgt = (const float*)d_in[7];
  const float* g_tgt = (const float*)d_in[8];
  const float* b_tgt = (const float*)d_in[9];
  const float* v_out = (const float*)d_in[10];
  const float* g_out = (const float*)d_in[11];
  const float* b_out = (const float*)d_in[12];

  char* w = (char*)d_ws;
  float* sumsq = (float*)w;
  size_t off = 256;
  u16* w_src = (u16*)(w + off); off += (size_t)2048 * 1024 * 2;
  u16* w_tgt = (u16*)(w + off); off += (size_t)1024 * 1024 * 2;
  u16* w_out = (u16*)(w + off); off += (size_t)1024 * 2048 * 2;
  u16* st    = (u16*)(w + off); off += (size_t)32768 * 1024 * 2;     // keys only
  u16* qb    = (u16*)(w + off); off += (size_t)16384 * 1024 * 2;     // tgt_trans
  u16* vt    = (u16*)(w + off); off += (size_t)256 * 128 * 1024 * 2; // V^T
  u16* cat   = (u16*)(w + off); off += (size_t)16384 * 2048 * 2;     // [tgt | tgt_update]
  u16* srcb  = cat;  // src bf16 alias (consumed by gemm1 before catleft/attn overwrite)

  hipMemsetAsync(sumsq, 0, 256, stream);
  sumsq3_k<<<384, 256, 0, stream>>>(v_src, v_tgt, v_out, sumsq);
  wconv3_k<<<5120, 256, 0, stream>>>(v_src, v_tgt, v_out, g_src, g_tgt, g_out,
                                     sumsq, w_src, w_tgt, w_out);
  cvt_k<<<32768, 256, 0, stream>>>(src, srcb);

  // src_trans: keys -> st, values -> vt (transposed), both masked  [32768 x 2048]
  gemm_bt256<2, true><<<dim3(8, 128), 512, 0, stream>>>(
      srcb, w_src, b_src, src_mask, (void*)st, vt, 1024, 1024, 0);
  catleft_k<<<16384, 256, 0, stream>>>(tgtf, cat);
  // tgt_trans = (tgt @ W_tgt^T + b_tgt) * tgt_mask   [16384 x 1024]
  gemm_bt256<1, true><<<dim3(4, 64), 512, 0, stream>>>(
      cat, w_tgt, b_tgt, tgt_mask, (void*)qb, nullptr, 1024, 2048, 1024);
  // flash attention -> cat[:, 1024:]
  attn_k<<<dim3(4, 8, 32), 256, 0, stream>>>(st, vt, qb, src_mask, cat);
  // out = cat @ W_out^T + b_out   [16384 x 1024] f32
  gemm_bt256<0, false><<<dim3(4, 64), 512, 0, stream>>>(
      cat, w_out, b_out, nullptr, d_out, nullptr, 2048, 2048, 1024);
}